// Round 8
// baseline (105.599 us; speedup 1.0000x reference)
//
#include <hip/hip_runtime.h>

// CurvatureLoss: B=4, N=4096, fp32.
// R8: R4-R7 books don't balance: ~22M wave-inst (~27 us at measured FMA
// rate) vs 50.5 us @ "95% busy". Residual ~ sum(VALU, L2 vector stream
// 1.07 GB ~31 us) => vmcnt/data-return serialization. Fix: lane=query
// transpose. Candidates are wave-uniform, staged once per block in a
// 16 KB LDS tile, read via broadcast ds_read_b128 (same addr all lanes,
// conflict-free). Vector traffic 1.07 GB -> 32 MB; zero vmcnt in loop.
// VALU/key unchanged; 8192 waves = 8/SIMD kept (2048 blocks: 256
// query-groups x 8 chunk-blocks; 4 waves/block x 128-cand chunks).
// 7-bit index embed (R3-proven), top-3 med3 + self-collapse, in-block
// 4-way merge, per-query partials -> merge+epilogue kernel.
// R7 path kept as fallback if ws_size < ~5.8 MB.

constexpr int BB   = 4;
constexpr int NN   = 4096;
constexpr int GQ   = 64;               // queries per group (= lanes)
constexpr int NGRP = BB * NN / GQ;     // 256 groups
constexpr int CHK  = 128;              // candidates per wave-chunk
constexpr int CPBLK= 4;                // chunks per block (= waves)
constexpr int BPG  = NN / CHK / CPBLK; // 8 chunk-blocks per group
constexpr int NBLK1= NGRP * BPG;       // 2048 blocks
constexpr float NEGBIG = -3.402823466e+38f;

__device__ __forceinline__ float fmed3(float a, float b, float c) {
    return __builtin_amdgcn_fmed3f(a, b, c);
}
__device__ __forceinline__ float embed7(float t, unsigned eb) {
    return __uint_as_float((__float_as_uint(t) & 0xFFFFFF80u) | eb);
}

// ---------------- new path ----------------
// candP[(b*NN+j)*2+0] = {ox,oy,oz,0.5|o|^2}; +1 = {ax,ay,az,0.5|a|^2}

__global__ __launch_bounds__(256) void pack2_kernel(
    const float* __restrict__ ori, const float* __restrict__ adv,
    float4* __restrict__ candP)
{
    const int i = blockIdx.x * blockDim.x + threadIdx.x;
    if (i < BB * NN) {
        float x = ori[3 * i], y = ori[3 * i + 1], z = ori[3 * i + 2];
        candP[2 * i]     = make_float4(x, y, z, 0.5f * (x * x + y * y + z * z));
        x = adv[3 * i]; y = adv[3 * i + 1]; z = adv[3 * i + 2];
        candP[2 * i + 1] = make_float4(x, y, z, 0.5f * (x * x + y * y + z * z));
    }
}

__global__ __launch_bounds__(256, 8) void knn_groups(
    const float4* __restrict__ candP, float* __restrict__ partial)
{
    const int tid  = threadIdx.x;
    const int lane = tid & 63;
    const int w    = tid >> 6;            // wave 0..3
    const int group= blockIdx.x >> 3;     // 0..255
    const int cb   = blockIdx.x & 7;      // chunk-block 0..7
    const int b    = group >> 6;          // batch
    const int g    = group & 63;          // group within batch
    const int c    = cb * CPBLK + w;      // chunk id within batch [0,32)

    __shared__ float4 lds4[1024];         // 16 KB tile, aliased for merge

    // stage 512 candidates (= 1024 float4), coalesced
    {
        const float4* __restrict__ src =
            candP + ((size_t)b * NN + cb * (CPBLK * CHK)) * 2;
        #pragma unroll
        for (int u = 0; u < 4; ++u)
            lds4[tid + 256 * u] = src[tid + 256 * u];
    }

    const int qb = g * GQ + lane;         // batch-local query index
    const float4 qo = candP[((size_t)b * NN + qb) * 2];
    const float4 qa = candP[((size_t)b * NN + qb) * 2 + 1];
    __syncthreads();

    // top-3 (max = closest); self key is guaranteed rank-1 when present
    float oA = NEGBIG, oB = NEGBIG, oC = NEGBIG;
    float aA = NEGBIG, aB = NEGBIG, aC = NEGBIG;
    float mm = NEGBIG;

    const float4* __restrict__ tile = lds4 + w * (CHK * 2);

    #pragma unroll 16
    for (int t = 0; t < CHK; ++t) {
        const float4 co = tile[2 * t];       // broadcast ds_read_b128
        const float4 ca = tile[2 * t + 1];
        const unsigned eb = (unsigned)(CHK - 1 - t);  // smaller t -> larger key

        float x;
        x = fmaf(qo.z, co.z, -co.w); x = fmaf(qo.y, co.y, x); x = fmaf(qo.x, co.x, x);
        const float ko = embed7(x, eb);
        x = fmaf(qa.z, co.z, -co.w); x = fmaf(qa.y, co.y, x); x = fmaf(qa.x, co.x, x);
        const float km = embed7(x, eb);
        x = fmaf(qa.z, ca.z, -ca.w); x = fmaf(qa.y, ca.y, x); x = fmaf(qa.x, ca.x, x);
        const float ka = embed7(x, eb);

        oC = fmed3(oB, oC, ko); oB = fmed3(oA, oB, ko); oA = fmaxf(oA, ko);
        aC = fmed3(aB, aC, ka); aB = fmed3(aA, aB, ka); aA = fmaxf(aA, ka);
        mm = fmaxf(mm, km);
    }

    // self-collapse: query qb is a candidate of chunk c iff qb>>7 == c
    if ((qb >> 7) == c) { oA = oB; oB = oC; aA = aB; aB = aC; }

    // batch-local indices
    const int base = c * CHK;
    const int io0 = base + (CHK - 1 - (int)(__float_as_uint(oA) & (CHK - 1u)));
    const int io1 = base + (CHK - 1 - (int)(__float_as_uint(oB) & (CHK - 1u)));
    const int ia0 = base + (CHK - 1 - (int)(__float_as_uint(aA) & (CHK - 1u)));
    const int ia1 = base + (CHK - 1 - (int)(__float_as_uint(aB) & (CHK - 1u)));
    const int im  = base + (CHK - 1 - (int)(__float_as_uint(mm) & (CHK - 1u)));

    __syncthreads();                      // tile no longer needed
    float* mg = (float*)lds4;             // [4][64][10]
    {
        float* my = mg + (w * 64 + lane) * 10;
        my[0] = oA; my[1] = oB; my[2] = aA; my[3] = aB; my[4] = mm;
        my[5] = __int_as_float(io0); my[6] = __int_as_float(io1);
        my[7] = __int_as_float(ia0); my[8] = __int_as_float(ia1);
        my[9] = __int_as_float(im);
    }
    __syncthreads();

    if (w == 0) {
        // lane merges query `lane` across the 4 waves (ascending w = ascending
        // chunk = ascending j; strict > keeps smaller index on ties)
        const float* p = mg + lane * 10;
        float ko0 = p[0], ko1 = p[1], ka0 = p[2], ka1 = p[3], km = p[4];
        int   jo0 = __float_as_int(p[5]), jo1 = __float_as_int(p[6]);
        int   ja0 = __float_as_int(p[7]), ja1 = __float_as_int(p[8]);
        int   jm  = __float_as_int(p[9]);
        #pragma unroll
        for (int ww = 1; ww < 4; ++ww) {
            const float* r = mg + (ww * 64 + lane) * 10;
            float c0, c1; int j0, j1;
            c0 = r[0]; c1 = r[1]; j0 = __float_as_int(r[5]); j1 = __float_as_int(r[6]);
            if (c0 > ko0)      { ko1 = ko0; jo1 = jo0; ko0 = c0; jo0 = j0; }
            else if (c0 > ko1) { ko1 = c0; jo1 = j0; }
            if (c1 > ko1)      { ko1 = c1; jo1 = j1; }
            c0 = r[2]; c1 = r[3]; j0 = __float_as_int(r[7]); j1 = __float_as_int(r[8]);
            if (c0 > ka0)      { ka1 = ka0; ja1 = ja0; ka0 = c0; ja0 = j0; }
            else if (c0 > ka1) { ka1 = c0; ja1 = j0; }
            if (c1 > ka1)      { ka1 = c1; ja1 = j1; }
            if (r[4] > km)     { km = r[4]; jm = __float_as_int(r[9]); }
        }
        float* dst = partial + ((size_t)(group * GQ + lane) * BPG + cb) * 10;
        dst[0] = ko0; dst[1] = ko1; dst[2] = ka0; dst[3] = ka1; dst[4] = km;
        dst[5] = __int_as_float(jo0); dst[6] = __int_as_float(jo1);
        dst[7] = __int_as_float(ja0); dst[8] = __int_as_float(ja1);
        dst[9] = __int_as_float(jm);
    }
}

__device__ __forceinline__ float unit_absdot_p(const float4 c,
                                               float px, float py, float pz,
                                               float nx, float ny, float nz) {
    const float vx = c.x - px, vy = c.y - py, vz = c.z - pz;
    const float s  = vx * vx + vy * vy + vz * vz + 1e-12f;
    return fabsf((vx * nx + vy * ny + vz * nz) * (1.0f / sqrtf(s)));
}

__global__ __launch_bounds__(256) void merge_epilogue(
    const float* __restrict__ partial, const float4* __restrict__ candP,
    const float* __restrict__ nrm, float* __restrict__ out)
{
    const int qq = blockIdx.x * 256 + threadIdx.x;   // 0..16383
    const int b  = qq >> 12;
    const int qb = qq & 4095;

    const float* p = partial + (size_t)qq * BPG * 10;
    float ko0 = p[0], ko1 = p[1], ka0 = p[2], ka1 = p[3], km = p[4];
    int   jo0 = __float_as_int(p[5]), jo1 = __float_as_int(p[6]);
    int   ja0 = __float_as_int(p[7]), ja1 = __float_as_int(p[8]);
    int   jm  = __float_as_int(p[9]);
    #pragma unroll
    for (int cb = 1; cb < BPG; ++cb) {
        const float* r = p + cb * 10;
        float c0, c1; int j0, j1;
        c0 = r[0]; c1 = r[1]; j0 = __float_as_int(r[5]); j1 = __float_as_int(r[6]);
        if (c0 > ko0)      { ko1 = ko0; jo1 = jo0; ko0 = c0; jo0 = j0; }
        else if (c0 > ko1) { ko1 = c0; jo1 = j0; }
        if (c1 > ko1)      { ko1 = c1; jo1 = j1; }
        c0 = r[2]; c1 = r[3]; j0 = __float_as_int(r[7]); j1 = __float_as_int(r[8]);
        if (c0 > ka0)      { ka1 = ka0; ja1 = ja0; ka0 = c0; ja0 = j0; }
        else if (c0 > ka1) { ka1 = c0; ja1 = j0; }
        if (c1 > ka1)      { ka1 = c1; ja1 = j1; }
        if (r[4] > km)     { km = r[4]; jm = __float_as_int(r[9]); }
    }

    const float4* __restrict__ cbp = candP + (size_t)b * NN * 2;
    const float*  __restrict__ nb  = nrm  + (size_t)b * NN * 3;

    const float4 qo = cbp[2 * qb], qa = cbp[2 * qb + 1];
    const float nx = nb[3 * qb], ny = nb[3 * qb + 1], nz = nb[3 * qb + 2];
    const float ok = 0.5f *
        (unit_absdot_p(cbp[2 * jo0], qo.x, qo.y, qo.z, nx, ny, nz) +
         unit_absdot_p(cbp[2 * jo1], qo.x, qo.y, qo.z, nx, ny, nz));
    const float ax = nb[3 * jm], ay = nb[3 * jm + 1], az = nb[3 * jm + 2];
    const float ak = 0.5f *
        (unit_absdot_p(cbp[2 * ja0 + 1], qa.x, qa.y, qa.z, ax, ay, az) +
         unit_absdot_p(cbp[2 * ja1 + 1], qa.x, qa.y, qa.z, ax, ay, az));
    const float d = ak - ok;
    float val = d * d;

    #pragma unroll
    for (int off = 32; off > 0; off >>= 1) val += __shfl_down(val, off);
    __shared__ float ls[4];
    if ((threadIdx.x & 63) == 0) ls[threadIdx.x >> 6] = val;
    __syncthreads();
    if (threadIdx.x == 0)
        atomicAdd(out, (ls[0] + ls[1] + ls[2] + ls[3]) * (1.0f / (float)(BB * NN)));
}

// ---------------- R7 fallback path (ws too small) ----------------

constexpr int QPB_F  = 8;
constexpr int NK_F   = 64;
constexpr int NBLK_F = BB * NN / QPB_F;

__global__ __launch_bounds__(256) void pack_kernel_f(
    const float* __restrict__ ori, const float* __restrict__ adv,
    float4* __restrict__ oriP, float4* __restrict__ advP)
{
    const int i = blockIdx.x * blockDim.x + threadIdx.x;
    if (i < BB * NN) {
        float x = ori[3 * i], y = ori[3 * i + 1], z = ori[3 * i + 2];
        oriP[i] = make_float4(x, y, z, 0.5f * (x * x + y * y + z * z));
        x = adv[3 * i]; y = adv[3 * i + 1]; z = adv[3 * i + 2];
        advP[i] = make_float4(x, y, z, 0.5f * (x * x + y * y + z * z));
    }
}

__device__ __forceinline__ float embed6(float t, unsigned eb) {
    return __uint_as_float((__float_as_uint(t) & 0xFFFFFFC0u) | eb);
}
__device__ __forceinline__ int recover_j_f(float v, float p0, float p1) {
    unsigned long long m = __ballot((p0 == v) || (p1 == v));
    const int lane = (int)__ffsll(m) - 1;
    const int k = (NK_F - 1) - (int)(__float_as_uint(v) & (unsigned)(NK_F - 1));
    return (k << 6) | lane;
}
__device__ __forceinline__ float unit_absdot4_f(const float4* __restrict__ pc, int i,
                                                float px, float py, float pz,
                                                float nx, float ny, float nz) {
    const float4 c = pc[i];
    const float vx = c.x - px, vy = c.y - py, vz = c.z - pz;
    const float s  = vx * vx + vy * vy + vz * vz + 1e-12f;
    return fabsf((vx * nx + vy * ny + vz * nz) * (1.0f / sqrtf(s)));
}

__global__ __launch_bounds__(256, 8) void knn_kernel_f(
    const float4* __restrict__ oriP, const float4* __restrict__ advP,
    const float* __restrict__ nrm, float* __restrict__ out)
{
    const int tid = threadIdx.x;
    const int ch  = tid & 63;
    const int qs  = tid >> 6;
    const int b   = blockIdx.x >> 9;
    const int qt  = blockIdx.x & 511;
    const int q0  = qt * QPB_F + qs * 2;
    const int q1  = q0 + 1;

    const float4* __restrict__ ob = oriP + (size_t)b * NN;
    const float4* __restrict__ ab = advP + (size_t)b * NN;
    const float*  __restrict__ nb = nrm  + (size_t)b * NN * 3;

    const float4 qo0 = ob[q0], qo1 = ob[q1];
    const float4 qa0 = ab[q0], qa1 = ab[q1];

    float oA0 = NEGBIG, oB0 = NEGBIG, oC0 = NEGBIG;
    float oA1 = NEGBIG, oB1 = NEGBIG, oC1 = NEGBIG;
    float aA0 = NEGBIG, aB0 = NEGBIG, aC0 = NEGBIG;
    float aA1 = NEGBIG, aB1 = NEGBIG, aC1 = NEGBIG;
    float m0  = NEGBIG, m1  = NEGBIG;

    const float4* __restrict__ op = ob + ch;
    const float4* __restrict__ ap = ab + ch;

    #pragma unroll 2
    for (int k = 0; k < NK_F; ++k) {
        const float4 co = op[k * 64];
        const float4 ca = ap[k * 64];
        const unsigned eb = (unsigned)(NK_F - 1 - k);
        float t;
        t = fmaf(qo0.z, co.z, -co.w); t = fmaf(qo0.y, co.y, t); t = fmaf(qo0.x, co.x, t);
        const float ko0 = embed6(t, eb);
        t = fmaf(qo1.z, co.z, -co.w); t = fmaf(qo1.y, co.y, t); t = fmaf(qo1.x, co.x, t);
        const float ko1 = embed6(t, eb);
        t = fmaf(qa0.z, co.z, -co.w); t = fmaf(qa0.y, co.y, t); t = fmaf(qa0.x, co.x, t);
        const float km0 = embed6(t, eb);
        t = fmaf(qa1.z, co.z, -co.w); t = fmaf(qa1.y, co.y, t); t = fmaf(qa1.x, co.x, t);
        const float km1 = embed6(t, eb);
        t = fmaf(qa0.z, ca.z, -ca.w); t = fmaf(qa0.y, ca.y, t); t = fmaf(qa0.x, ca.x, t);
        const float ka0 = embed6(t, eb);
        t = fmaf(qa1.z, ca.z, -ca.w); t = fmaf(qa1.y, ca.y, t); t = fmaf(qa1.x, ca.x, t);
        const float ka1 = embed6(t, eb);

        oC0 = fmed3(oB0, oC0, ko0); oB0 = fmed3(oA0, oB0, ko0); oA0 = fmaxf(oA0, ko0);
        oC1 = fmed3(oB1, oC1, ko1); oB1 = fmed3(oA1, oB1, ko1); oA1 = fmaxf(oA1, ko1);
        aC0 = fmed3(aB0, aC0, ka0); aB0 = fmed3(aA0, aB0, ka0); aA0 = fmaxf(aA0, ka0);
        aC1 = fmed3(aB1, aC1, ka1); aB1 = fmed3(aA1, aB1, ka1); aA1 = fmaxf(aA1, ka1);
        m0  = fmaxf(m0, km0);
        m1  = fmaxf(m1, km1);
    }

    const bool s0 = ((q0 & 63) == ch);
    const bool s1 = ((q1 & 63) == ch);
    oA0 = s0 ? oB0 : oA0;  oB0 = s0 ? oC0 : oB0;
    aA0 = s0 ? aB0 : aA0;  aB0 = s0 ? aC0 : aB0;
    oA1 = s1 ? oB1 : oA1;  oB1 = s1 ? oC1 : oB1;
    aA1 = s1 ? aB1 : aA1;  aB1 = s1 ? aC1 : aB1;

    const float soA0 = oA0, soB0 = oB0, soA1 = oA1, soB1 = oB1;
    const float saA0 = aA0, saB0 = aB0, saA1 = aA1, saB1 = aB1;
    const float sm0 = m0, sm1 = m1;

    #pragma unroll
    for (int off = 1; off < 64; off <<= 1) {
        float r0, r1, mn;
        r0 = __shfl_xor(oA0, off); r1 = __shfl_xor(oB0, off);
        mn = fminf(oA0, r0); oA0 = fmaxf(oA0, r0); oB0 = fmaxf(mn, fmaxf(oB0, r1));
        r0 = __shfl_xor(oA1, off); r1 = __shfl_xor(oB1, off);
        mn = fminf(oA1, r0); oA1 = fmaxf(oA1, r0); oB1 = fmaxf(mn, fmaxf(oB1, r1));
        r0 = __shfl_xor(aA0, off); r1 = __shfl_xor(aB0, off);
        mn = fminf(aA0, r0); aA0 = fmaxf(aA0, r0); aB0 = fmaxf(mn, fmaxf(aB0, r1));
        r0 = __shfl_xor(aA1, off); r1 = __shfl_xor(aB1, off);
        mn = fminf(aA1, r0); aA1 = fmaxf(aA1, r0); aB1 = fmaxf(mn, fmaxf(aB1, r1));
        m0 = fmaxf(m0, __shfl_xor(m0, off));
        m1 = fmaxf(m1, __shfl_xor(m1, off));
    }

    const int jo0_0 = recover_j_f(oA0, soA0, soB0);
    const int jo1_0 = recover_j_f(oB0, soA0, soB0);
    const int jo0_1 = recover_j_f(oA1, soA1, soB1);
    const int jo1_1 = recover_j_f(oB1, soA1, soB1);
    const int ja0_0 = recover_j_f(aA0, saA0, saB0);
    const int ja1_0 = recover_j_f(aB0, saA0, saB0);
    const int ja0_1 = recover_j_f(aA1, saA1, saB1);
    const int ja1_1 = recover_j_f(aB1, saA1, saB1);
    const int jm_0  = recover_j_f(m0, sm0, sm0);
    const int jm_1  = recover_j_f(m1, sm1, sm1);

    float val = 0.0f;
    if (ch < 2) {
        const int    q  = ch ? q1 : q0;
        const float4 qo = ch ? qo1 : qo0;
        const float4 qa = ch ? qa1 : qa0;
        const int io0 = ch ? jo0_1 : jo0_0;
        const int io1 = ch ? jo1_1 : jo1_0;
        const int ia0 = ch ? ja0_1 : ja0_0;
        const int ia1 = ch ? ja1_1 : ja1_0;
        const int im  = ch ? jm_1  : jm_0;

        const float nx = nb[3 * q], ny = nb[3 * q + 1], nz = nb[3 * q + 2];
        const float ok = 0.5f * (unit_absdot4_f(ob, io0, qo.x, qo.y, qo.z, nx, ny, nz) +
                                 unit_absdot4_f(ob, io1, qo.x, qo.y, qo.z, nx, ny, nz));
        const float ax = nb[3 * im], ay = nb[3 * im + 1], az = nb[3 * im + 2];
        const float ak = 0.5f * (unit_absdot4_f(ab, ia0, qa.x, qa.y, qa.z, ax, ay, az) +
                                 unit_absdot4_f(ab, ia1, qa.x, qa.y, qa.z, ax, ay, az));
        const float d = ak - ok;
        val = d * d;
    }
    val += __shfl_down(val, 1);

    __shared__ float sval[4];
    if (ch == 0) sval[qs] = val;
    __syncthreads();
    if (tid == 0)
        atomicAdd(out, (sval[0] + sval[1] + sval[2] + sval[3]) * (1.0f / (float)(BB * NN)));
}

// ---------------- launch ----------------

extern "C" void kernel_launch(void* const* d_in, const int* in_sizes, int n_in,
                              void* d_out, int out_size, void* d_ws, size_t ws_size,
                              hipStream_t stream) {
    const float* ori = (const float*)d_in[0];
    const float* adv = (const float*)d_in[1];
    const float* nrm = (const float*)d_in[2];
    float* out = (float*)d_out;

    const size_t candBytes = (size_t)BB * NN * 2 * sizeof(float4);          // 512 KB
    const size_t partBytes = (size_t)NGRP * GQ * BPG * 10 * sizeof(float);  // 5.24 MB

    hipMemsetAsync(out, 0, sizeof(float), stream);

    if (ws_size >= candBytes + partBytes) {
        float4* candP = (float4*)d_ws;
        float*  part  = (float*)((char*)d_ws + candBytes);
        hipLaunchKernelGGL(pack2_kernel, dim3((BB * NN + 255) / 256), dim3(256),
                           0, stream, ori, adv, candP);
        hipLaunchKernelGGL(knn_groups, dim3(NBLK1), dim3(256), 0, stream,
                           candP, part);
        hipLaunchKernelGGL(merge_epilogue, dim3(NGRP * GQ / 256), dim3(256),
                           0, stream, part, candP, nrm, out);
    } else {
        float4* oriP = (float4*)d_ws;
        float4* advP = oriP + (size_t)BB * NN;
        hipLaunchKernelGGL(pack_kernel_f, dim3((BB * NN + 255) / 256), dim3(256),
                           0, stream, ori, adv, oriP, advP);
        hipLaunchKernelGGL(knn_kernel_f, dim3(NBLK_F), dim3(256), 0, stream,
                           oriP, advP, nrm, out);
    }
}